// Round 5
// baseline (190.288 us; speedup 1.0000x reference)
//
#include <hip/hip_runtime.h>

// DIAGNOSTIC ROUND: round-2 structure, replicated 4x via blockIdx.y so the
// matcher dispatch finally exceeds the harness's ~60us poison fills and
// surfaces in the rocprof top-5 with its own counters.
//   y=0 -> d_out (the real output, unchanged semantics)
//   y=1..3 -> d_ws + (y-1)*23.04M floats (276.48 MB ws holds exactly 3 replicas)
// (dur_us - 121.4)/3 ~= true matcher time M. Next round reverts to the best
// single-shot kernel armed with real counters.

#define BLOCK 256
#define QPB 8
#define NC 91
#define NT 1600
#define TSLOTS ((NT + BLOCK - 1) / BLOCK)   // 7
#define REPL_ELEMS (14400 * (size_t)NT)     // 23,040,000 floats = 92.16 MB

__global__ __launch_bounds__(BLOCK, 4) void matcher_kernel(
    const float* __restrict__ logits,   // [14400, 91]
    const float* __restrict__ pboxes,   // [14400, 4] cxcywh
    const float* __restrict__ tboxes,   // [1600, 4]  cxcywh
    const int*   __restrict__ tids,     // [1600]
    float*       __restrict__ out,      // [14400, 1600]
    float*       __restrict__ ws)       // >= 3 * REPL_ELEMS floats
{
    __shared__ float s_cc[QPB * NC];
    const int tid = threadIdx.x;
    const int q0  = blockIdx.x * QPB;
    const int y   = blockIdx.y;
    float* obase = (y == 0) ? out : (ws + (size_t)(y - 1) * REPL_ELEMS);

    // --- Phase A1: focal class costs for this block's 8 queries (COST_CLASS=2 folded).
    for (int i = tid; i < QPB * NC; i += BLOCK) {
        float x   = logits[(size_t)q0 * NC + i];
        float p   = 1.0f / (1.0f + __expf(-x));
        float omp = 1.0f - p;
        float pos = 0.25f * omp * omp * (-__logf(p   + 1e-8f));
        float neg = 0.75f * p   * p   * (-__logf(omp + 1e-8f));
        s_cc[i] = 2.0f * (pos - neg);
    }

    // --- Phase A2: stage this thread's 7 targets into registers.
    float4 tb[TSLOTS], xy[TSLOTS];
    int    ida[TSLOTS];
    #pragma unroll
    for (int k = 0; k < TSLOTS; ++k) {
        int t = tid + k * BLOCK;
        if (t < NT) {
            float4 b = ((const float4*)tboxes)[t];
            tb[k] = b;
            xy[k] = make_float4(fmaf(-0.5f, b.z, b.x), fmaf(-0.5f, b.w, b.y),
                                fmaf( 0.5f, b.z, b.x), fmaf( 0.5f, b.w, b.y));
            ida[k] = tids[t];
        }
    }
    __syncthreads();

    // --- Phase B: 8 queries x 7 register-resident targets.
    #pragma unroll 1
    for (int q = 0; q < QPB; ++q) {
        const int    qg = q0 + q;
        const float4 qb = ((const float4*)pboxes)[qg];     // L1 broadcast
        const float qx0 = fmaf(-0.5f, qb.z, qb.x), qy0 = fmaf(-0.5f, qb.w, qb.y);
        const float qx1 = fmaf( 0.5f, qb.z, qb.x), qy1 = fmaf( 0.5f, qb.w, qb.y);
        const float qarea = qb.z * qb.w;
        const float* cc   = s_cc + q * NC;
        float* outq = obase + (size_t)qg * NT;

        #pragma unroll
        for (int k = 0; k < TSLOTS; ++k) {
            int t = tid + k * BLOCK;
            if (t < NT) {                                  // wave-uniform (k=6: wave 0 only)
                float4 b = tb[k], p = xy[k];

                float l1 = fabsf(qb.x - b.x) + fabsf(qb.y - b.y)
                         + fabsf(qb.z - b.z) + fabsf(qb.w - b.w);

                float tarea = b.z * b.w;
                float iw = fminf(qx1, p.z) - fmaxf(qx0, p.x);
                float ih = fminf(qy1, p.w) - fmaxf(qy0, p.y);
                float inter = fmaxf(iw, 0.0f) * fmaxf(ih, 0.0f);
                float uni   = qarea + tarea - inter;
                float iou   = inter * __builtin_amdgcn_rcpf(uni);
                float ew = fmaxf(qx1, p.z) - fminf(qx0, p.x);
                float eh = fmaxf(qy1, p.w) - fminf(qy0, p.y);
                float earea = ew * eh;
                float giou  = iou - (earea - uni) * __builtin_amdgcn_rcpf(earea);

                outq[t] = fmaf(5.0f, l1, cc[ida[k]]) - 2.0f * giou;
            }
        }
    }
}

extern "C" void kernel_launch(void* const* d_in, const int* in_sizes, int n_in,
                              void* d_out, int out_size, void* d_ws, size_t ws_size,
                              hipStream_t stream) {
    const float* logits = (const float*)d_in[0];   // (16,900,91) fp32
    const float* pboxes = (const float*)d_in[1];   // (16,900,4)  fp32
    const float* tboxes = (const float*)d_in[2];   // (1600,4)    fp32
    const int*   tids   = (const int*)d_in[3];     // (1600,)     int32

    const int nqall = in_sizes[1] / 4;             // 14400
    float* out = (float*)d_out;
    float* ws  = (float*)d_ws;

    dim3 grid(nqall / QPB, 4);                     // y: 1 real + 3 replicas
    matcher_kernel<<<grid, BLOCK, 0, stream>>>(logits, pboxes, tboxes,
                                               tids, out, ws);
}